// Round 1
// 371.656 us; speedup vs baseline: 1.0317x; 1.0317x over previous
//
#include <hip/hip_runtime.h>
#include <hip/hip_bf16.h>
#include <math.h>

// bf16 stored as short (raw bits); fp32 accumulate in MFMA.
using bf16x8 = __attribute__((ext_vector_type(8))) short;
using f32x4  = __attribute__((ext_vector_type(4))) float;
using i32x4  = __attribute__((ext_vector_type(4))) int;

#define MFMA_BF16(a, b, c) __builtin_amdgcn_mfma_f32_16x16x32_bf16((a), (b), (c), 0, 0, 0)

__device__ __forceinline__ float bf2f(short s) {
    union { unsigned u; float f; } v;
    v.u = ((unsigned)(unsigned short)s) << 16;
    return v.f;
}
__device__ __forceinline__ short f2bf(float f) {
    union { float f; unsigned u; } v; v.f = f;
    unsigned r = v.u + 0x7FFF + ((v.u >> 16) & 1);  // round-to-nearest-even
    return (short)(r >> 16);
}
// Pack two fp32 -> dword of two bf16 (round-half-up) in ~3 ops via v_perm.
__device__ __forceinline__ int pack_bf16_rhu(float lo, float hi) {
    union { float f; unsigned u; } a, b; a.f = lo; b.f = hi;
    unsigned x = a.u + 0x8000u, y = b.u + 0x8000u;
#if __has_builtin(__builtin_amdgcn_perm)
    return (int)__builtin_amdgcn_perm(y, x, 0x07060302u);  // {y.hi16, x.hi16}
#else
    return (int)((y & 0xFFFF0000u) | (x >> 16));
#endif
}
// Raw 2^x (v_exp_f32). Q is pre-scaled by log2(e)/8 so this IS exp(score).
__device__ __forceinline__ float fexp2(float x) {
#if __has_builtin(__builtin_amdgcn_exp2f)
    return __builtin_amdgcn_exp2f(x);
#else
    return exp2f(x);
#endif
}

// Async global->LDS DMA, 16B per lane (LDS dest = wave base + lane*16).
__device__ __forceinline__ void gload_lds16(const void* g, void* l) {
    __builtin_amdgcn_global_load_lds(
        (const __attribute__((address_space(1))) void*)g,
        (__attribute__((address_space(3))) void*)l, 16, 0, 0);
}

// ---------------------------------------------------------------------------
// Input dtype detector (proven R3). flag: 1=bf16, 0=fp32.
// ---------------------------------------------------------------------------
__global__ void detect_dtype(const unsigned short* __restrict__ emb, int* flag) {
    __shared__ int tot;
    if (threadIdx.x == 0) tot = 0;
    __syncthreads();
    int c = 0;
    for (int i = 0; i < 64; i++) {
        unsigned short v = emb[2 * (threadIdx.x * 64 + i)];
        unsigned e = (v >> 7) & 0xFF;
        if (v == 0 || v == 0x8000u || (e >= 97 && e <= 137)) c++;
    }
    atomicAdd(&tot, c);
    __syncthreads();
    if (threadIdx.x == 0) *flag = (tot > 8192) ? 1 : 0;
}

__global__ void convert8(const void* __restrict__ src, short* __restrict__ dst,
                         int n8, const int* __restrict__ flag) {
    int i = blockIdx.x * 256 + threadIdx.x;
    if (i >= n8) return;
    if (*flag) {
        ((bf16x8*)dst)[i] = ((const bf16x8*)src)[i];
    } else {
        const float* f = (const float*)src + (size_t)i * 8;
        bf16x8 o;
#pragma unroll
        for (int j = 0; j < 8; j++) o[j] = f2bf(f[j]);
        ((bf16x8*)dst)[i] = o;
    }
}

// All 4 weights (131072 n8 each) + 4 biases (128 n8 each) in ONE launch.
// Grid = 2050 blocks x 256 = 524800 = 4*131072 + 4*128 exactly.
__global__ void convert_all(
    const void* __restrict__ w0, const void* __restrict__ w1,
    const void* __restrict__ w2, const void* __restrict__ w3,
    const void* __restrict__ b0, const void* __restrict__ b1,
    const void* __restrict__ b2, const void* __restrict__ b3,
    short* dw0, short* dw1, short* dw2, short* dw3,
    short* db0, short* db1, short* db2, short* db3,
    const int* __restrict__ flag)
{
    int i = blockIdx.x * 256 + threadIdx.x;
    const void* src; short* dst; int idx;
    if (i < 524288) {
        int w = i >> 17; idx = i & 131071;
        src = (w == 0) ? w0 : (w == 1) ? w1 : (w == 2) ? w2 : w3;
        dst = (w == 0) ? dw0 : (w == 1) ? dw1 : (w == 2) ? dw2 : dw3;
    } else {
        int j = i - 524288; int b = j >> 7; idx = j & 127;
        src = (b == 0) ? b0 : (b == 1) ? b1 : (b == 2) ? b2 : b3;
        dst = (b == 0) ? db0 : (b == 1) ? db1 : (b == 2) ? db2 : db3;
    }
    if (*flag) {
        ((bf16x8*)dst)[idx] = ((const bf16x8*)src)[idx];
    } else {
        const float* f = (const float*)src + (size_t)idx * 8;
        bf16x8 o;
#pragma unroll
        for (int j = 0; j < 8; j++) o[j] = f2bf(f[j]);
        ((bf16x8*)dst)[idx] = o;
    }
}

// ---------------------------------------------------------------------------
// m97-style GEMM (proven R7): 128x128 tile, BK=32, global_load_lds staging.
// mode: 0 = bf16 natural, 1 = bf16 transposed (Vt), 2 = per *flag dtype.
// ---------------------------------------------------------------------------
__global__ __launch_bounds__(256) void gemm128(
    const short* __restrict__ A,
    const short* __restrict__ B0, const short* __restrict__ B1,
    const short* __restrict__ B2,
    const short* __restrict__ bias0, const short* __restrict__ bias1,
    const short* __restrict__ bias2,
    void* __restrict__ C0, void* __restrict__ C1, void* __restrict__ C2,
    float s0, float s1, float s2,
    int mode0, int mode1, int mode2,
    const int* __restrict__ flag)
{
    constexpr int M = 8192, N = 1024, Kd = 1024, BK = 32;
    __shared__ __align__(16) short As[128 * BK];
    __shared__ __align__(16) short Bs[128 * BK];

    const int z = blockIdx.z;
    const short* B    = (z == 0) ? B0    : (z == 1) ? B1    : B2;
    const short* bias = (z == 0) ? bias0 : (z == 1) ? bias1 : bias2;
    void*  C     = (z == 0) ? C0 : (z == 1) ? C1 : C2;
    float  scale = (z == 0) ? s0 : (z == 1) ? s1 : s2;
    int    mode  = (z == 0) ? mode0 : (z == 1) ? mode1 : mode2;

    const int tid  = threadIdx.x;
    const int lane = tid & 63;
    const int wave = tid >> 6;
    const int lr   = lane & 15;
    const int quad = lane >> 4;
    const int q8   = quad * 8;

    const int m0 = (blockIdx.x >> 3) * 128;
    const int n0 = (blockIdx.x & 7) * 128;
    const int wm = (wave >> 1) * 64;
    const int wn = (wave & 1) * 64;

    const int srow = lane >> 2;
    const int scol = (lane & 3) * 8;

    int fl = 1;
    if (mode == 2) fl = *flag;

    f32x4 acc[4][4];
#pragma unroll
    for (int i = 0; i < 4; i++)
#pragma unroll
        for (int j = 0; j < 4; j++) acc[i][j] = (f32x4){0.f, 0.f, 0.f, 0.f};

    for (int k0 = 0; k0 < Kd; k0 += BK) {
#pragma unroll
        for (int t = 0; t < 2; t++) {
            const int r = wave * 32 + t * 16;
            gload_lds16(A + (size_t)(m0 + r + srow) * Kd + k0 + scol,
                        As + r * BK);
            gload_lds16(B + (size_t)(n0 + r + srow) * Kd + k0 + scol,
                        Bs + r * BK);
        }
        __syncthreads();

        bf16x8 a[4], b[4];
#pragma unroll
        for (int i = 0; i < 4; i++)
            a[i] = *(const bf16x8*)(As + (wm + i * 16 + lr) * BK + q8);
#pragma unroll
        for (int j = 0; j < 4; j++)
            b[j] = *(const bf16x8*)(Bs + (wn + j * 16 + lr) * BK + q8);
#pragma unroll
        for (int i = 0; i < 4; i++)
#pragma unroll
            for (int j = 0; j < 4; j++)
                acc[i][j] = MFMA_BF16(a[i], b[j], acc[i][j]);
        __syncthreads();
    }

#pragma unroll
    for (int j = 0; j < 4; j++) {
        const int col = n0 + wn + j * 16 + lr;
        const float bv = bf2f(bias[col]);
#pragma unroll
        for (int i = 0; i < 4; i++) {
#pragma unroll
            for (int r = 0; r < 4; r++) {
                const int row = m0 + wm + i * 16 + quad * 4 + r;
                const float v = (acc[i][j][r] + bv) * scale;
                if (mode == 1)      ((short*)C)[(size_t)col * M + row] = f2bf(v);
                else if (mode == 0) ((short*)C)[(size_t)row * N + col] = f2bf(v);
                else {
                    if (fl) ((short*)C)[(size_t)row * N + col] = f2bf(v);
                    else    ((float*)C)[(size_t)row * N + col] = v;
                }
            }
        }
    }
}

// ---------------------------------------------------------------------------
// Flash attention R9: R8 softmax/permute structure + async double-buffered
// K/V staging (T3-lite):
//  - global_load_lds (16B) DMA, no reg round-trip, no ds_writes.
//  - tile t+1 DMA issued BEFORE consuming tile t; counted s_waitcnt vmcnt(4)
//    (never 0) + raw s_barrier -> next tile's loads stay in flight across the
//    barrier; load latency hides under compute.
//  - LDS linear [64][64] (gload_lds needs linear dest); bank conflicts fixed
//    by both-sides XOR chunk swizzle: source chunk pre-swizzled per lane by
//    (lane&7)^(lane>>3); reads use chunk = (kk*4+quad)^(row&7). LDS chunk c
//    of row r holds global chunk c^(r&7) (chunk = 8 shorts = 16B).
// S^T = K.Q^T; P C-layout -> A-frags via lane permutes (verified R5).
// Aout may alias Q: each block reads only the Q region it alone writes.
// ---------------------------------------------------------------------------
__global__ __launch_bounds__(256) void attn_kernel(
    const short* Q, const short* __restrict__ K,
    const short* __restrict__ Vt, short* Aout)
{
    // [buf][0]=K tile [k 0..63][64 shorts], [buf][1]=V tile [d 0..63][64 shorts]
    __shared__ __align__(16) short lds[2][2][64][64];   // 32 KiB

    const int tid  = threadIdx.x;
    const int lane = tid & 63;
    const int wave = tid >> 6;
    const int lr   = lane & 15;
    const int quad = lane >> 4;
    const int q8   = quad * 8;

    const int qt = blockIdx.x;
    const int bh = blockIdx.y;
    const int b  = bh >> 4, h = bh & 15;
    const int q0 = b * 2048 + qt * 64 + wave * 16;
    const int c0 = h * 64;

    // staging geometry: lane l covers row (base + l>>3), 16B chunk l&7 in LDS;
    // source chunk is XOR-swizzled so LDS row r chunk c holds global c^(r&7).
    const int sr = lane >> 3;
    const int sc = ((lane & 7) ^ sr) * 8;      // shorts
    const int sarr = wave >> 1;                // waves 0,1 -> K; 2,3 -> V

    const short* Kb = K  + (size_t)(b * 2048) * 1024 + c0;
    const short* Vb = Vt + (size_t)c0 * 8192 + b * 2048;

    bf16x8 qf[2];
#pragma unroll
    for (int kk = 0; kk < 2; kk++)
        qf[kk] = *(const bf16x8*)(Q + (size_t)(q0 + lr) * 1024 + c0 + kk * 32 + q8);

    // 4 DMA calls per wave per tile (waves 0,1 stage K rows, 2,3 stage V rows)
    auto stage = [&](int bufi, int kt) {
#pragma unroll
        for (int t = 0; t < 4; t++) {
            const int r0 = ((wave & 1) * 4 + t) * 8;
            short* dst = &lds[bufi][sarr][r0][0];       // wave-uniform base
            if (sarr == 0)
                gload_lds16(Kb + (size_t)(kt + r0 + sr) * 1024 + sc, dst);
            else
                gload_lds16(Vb + (size_t)(r0 + sr) * 8192 + kt + sc, dst);
        }
    };

    float l_run = 0.f;
    f32x4 o[4];
#pragma unroll
    for (int d = 0; d < 4; d++) o[d] = (f32x4){0.f, 0.f, 0.f, 0.f};

    const int xr = lr & 7;   // row&7 for all fragment rows (j*16+lr etc.)

    stage(0, 0);
    for (int kt = 0; kt < 2048; kt += 64) {
        const int cur = (kt >> 6) & 1;
        stage(cur ^ 1, (kt + 64) & 2047);   // last iter wraps: harmless re-stage
        asm volatile("s_waitcnt vmcnt(4)" ::: "memory");  // tile cur complete
        __builtin_amdgcn_s_barrier();
        __builtin_amdgcn_sched_barrier(0);

        f32x4 s[4];
#pragma unroll
        for (int j = 0; j < 4; j++) s[j] = (f32x4){0.f, 0.f, 0.f, 0.f};
#pragma unroll
        for (int j = 0; j < 4; j++)
#pragma unroll
            for (int kk = 0; kk < 2; kk++) {
                bf16x8 kf = *(const bf16x8*)
                    &lds[cur][0][j * 16 + lr][((kk * 4 + quad) ^ xr) * 8];
                s[j] = MFMA_BF16(kf, qf[kk], s[j]);
            }

        float rs = 0.f;
#pragma unroll
        for (int j = 0; j < 4; j++)
#pragma unroll
            for (int r = 0; r < 4; r++) {
                float p = fexp2(s[j][r]);   // scores are log2-domain
                s[j][r] = p;
                rs += p;
            }
        rs += __shfl_xor(rs, 16);
        rs += __shfl_xor(rs, 32);
        l_run += rs;

        int p01[4], p23[4];
#pragma unroll
        for (int j = 0; j < 4; j++) {
            p01[j] = pack_bf16_rhu(s[j][0], s[j][1]);
            p23[j] = pack_bf16_rhu(s[j][2], s[j][3]);
        }
        const int jhi = quad >> 1;
#pragma unroll
        for (int kk = 0; kk < 2; kk++) {
            i32x4 fr;
#pragma unroll
            for (int d = 0; d < 4; d++) {
                const int src = (((quad & 1) * 2 + (d >> 1)) << 4) + lr;
                const int lo = __shfl((d & 1) ? p23[2 * kk]     : p01[2 * kk],     src);
                const int hi = __shfl((d & 1) ? p23[2 * kk + 1] : p01[2 * kk + 1], src);
                fr[d] = jhi ? hi : lo;
            }
            const bf16x8 pf = *(const bf16x8*)&fr;
#pragma unroll
            for (int d = 0; d < 4; d++) {
                bf16x8 vf = *(const bf16x8*)
                    &lds[cur][1][d * 16 + lr][((kk * 4 + quad) ^ xr) * 8];
                o[d] = MFMA_BF16(pf, vf, o[d]);
            }
        }
        // All ds_reads/bpermutes are consumed above (lgkmcnt naturally 0);
        // explicit drain is free and guards buffer reuse across the barrier.
        asm volatile("s_waitcnt lgkmcnt(0)" ::: "memory");
        __builtin_amdgcn_sched_barrier(0);
        __builtin_amdgcn_s_barrier();
    }

    float l_o[4];
#pragma unroll
    for (int r = 0; r < 4; r++) l_o[r] = __shfl(l_run, quad * 4 + r);
#pragma unroll
    for (int d = 0; d < 4; d++)
#pragma unroll
        for (int r = 0; r < 4; r++) {
            float v = o[d][r] / l_o[r];
            Aout[(size_t)(q0 + quad * 4 + r) * 1024 + c0 + d * 16 + lr] = f2bf(v);
        }
}

// ---------------------------------------------------------------------------
extern "C" void kernel_launch(void* const* d_in, const int* in_sizes, int n_in,
                              void* d_out, int out_size, void* d_ws, size_t ws_size,
                              hipStream_t stream)
{
    const size_t MB = (size_t)1024 * 1024;
    char* ws = (char*)d_ws;

    int*   flagp = (int*)ws;                 // [0, 256)
    short* embC  = (short*)(ws + 1 * MB);    // 16 MB [8192][1024]
    short* wC[4] = { (short*)(ws + 17 * MB), (short*)(ws + 19 * MB),
                     (short*)(ws + 21 * MB), (short*)(ws + 23 * MB) };  // 2 MB ea
    short* bC[4] = { (short*)(ws + 25 * MB), (short*)(ws + 25 * MB + 4096),
                     (short*)(ws + 25 * MB + 8192), (short*)(ws + 25 * MB + 12288) };

    short *Qb, *Kb, *Vt, *Ab;
    if (ws_size >= 90 * MB) {
        Qb = (short*)(ws + 26 * MB);
        Kb = (short*)(ws + 42 * MB);
        Vt = (short*)(ws + 58 * MB);
        Ab = (short*)(ws + 74 * MB);
    } else {
        Qb = (short*)(ws + 26 * MB);
        Kb = (short*)d_out;      // dead after attention; final GEMM rewrites
        Vt = (short*)(ws + 42 * MB);
        Ab = Qb;                 // alias: safe per attn_kernel note
    }

    detect_dtype<<<1, 256, 0, stream>>>((const unsigned short*)d_in[0], flagp);

    convert8<<<4096, 256, 0, stream>>>(d_in[0], embC, 1048576, flagp);   // emb
    convert_all<<<2050, 256, 0, stream>>>(
        d_in[1], d_in[3], d_in[5], d_in[7],
        d_in[2], d_in[4], d_in[6], d_in[8],
        wC[0], wC[1], wC[2], wC[3],
        bC[0], bC[1], bC[2], bC[3], flagp);

    dim3 blk(256);
    // Fused QKV; Q scale = log2(e)/8 (log2-domain softmax, see attn header).
    gemm128<<<dim3(512, 1, 3), blk, 0, stream>>>(
        embC, wC[0], wC[1], wC[2], bC[0], bC[1], bC[2],
        Qb, Kb, Vt, 0.18033688011112042f, 1.0f, 1.0f, 0, 0, 1, nullptr);

    attn_kernel<<<dim3(32, 64), blk, 0, stream>>>(Qb, Kb, Vt, Ab);

    gemm128<<<dim3(512, 1, 1), blk, 0, stream>>>(
        Ab, wC[3], nullptr, nullptr, bC[3], nullptr, nullptr,
        d_out, nullptr, nullptr, 1.0f, 0.f, 0.f, 2, 0, 0, flagp);
}

// Round 2
// 330.302 us; speedup vs baseline: 1.1609x; 1.1252x over previous
//
#include <hip/hip_runtime.h>
#include <hip/hip_bf16.h>
#include <math.h>

// bf16 stored as short (raw bits); fp32 accumulate in MFMA.
using bf16x8 = __attribute__((ext_vector_type(8))) short;
using f32x4  = __attribute__((ext_vector_type(4))) float;
using f32x16 = __attribute__((ext_vector_type(16))) float;
using i32x4  = __attribute__((ext_vector_type(4))) int;

#define MFMA_BF16(a, b, c) __builtin_amdgcn_mfma_f32_16x16x32_bf16((a), (b), (c), 0, 0, 0)
#define MFMA32(a, b, c)    __builtin_amdgcn_mfma_f32_32x32x16_bf16((a), (b), (c), 0, 0, 0)

__device__ __forceinline__ float bf2f(short s) {
    union { unsigned u; float f; } v;
    v.u = ((unsigned)(unsigned short)s) << 16;
    return v.f;
}
__device__ __forceinline__ short f2bf(float f) {
    union { float f; unsigned u; } v; v.f = f;
    unsigned r = v.u + 0x7FFF + ((v.u >> 16) & 1);  // round-to-nearest-even
    return (short)(r >> 16);
}
// Pack two fp32 -> dword of two bf16 (round-half-up) in ~3 ops via v_perm.
__device__ __forceinline__ int pack_bf16_rhu(float lo, float hi) {
    union { float f; unsigned u; } a, b; a.f = lo; b.f = hi;
    unsigned x = a.u + 0x8000u, y = b.u + 0x8000u;
#if __has_builtin(__builtin_amdgcn_perm)
    return (int)__builtin_amdgcn_perm(y, x, 0x07060302u);  // {y.hi16, x.hi16}
#else
    return (int)((y & 0xFFFF0000u) | (x >> 16));
#endif
}
// Native packed f32->bf16 convert (RNE), 1 VALU op for 2 values.
__device__ __forceinline__ int cvtpk_bf16(float lo, float hi) {
    int r;
    asm("v_cvt_pk_bf16_f32 %0, %1, %2" : "=v"(r) : "v"(lo), "v"(hi));
    return r;
}
// v_permlane32_swap_b32: a'[l<32]=a[l], a'[32+i]=b[i]; b'[i]=a[32+i], b'[32+i]=b[32+i].
__device__ __forceinline__ void permswap(int &a, int &b) {
#if __has_builtin(__builtin_amdgcn_permlane32_swap)
    typedef unsigned u32x2v __attribute__((ext_vector_type(2)));
    u32x2v r = __builtin_amdgcn_permlane32_swap((unsigned)a, (unsigned)b, false, false);
    a = (int)r[0]; b = (int)r[1];
#else
    asm volatile("v_permlane32_swap_b32 %0, %1" : "+v"(a), "+v"(b));
#endif
}
// Raw 2^x (v_exp_f32). Q is pre-scaled by log2(e)/8 so this IS exp(score).
__device__ __forceinline__ float fexp2(float x) {
#if __has_builtin(__builtin_amdgcn_exp2f)
    return __builtin_amdgcn_exp2f(x);
#else
    return exp2f(x);
#endif
}

// Async global->LDS DMA, 16B per lane (LDS dest = wave base + lane*16).
__device__ __forceinline__ void gload_lds16(const void* g, void* l) {
    __builtin_amdgcn_global_load_lds(
        (const __attribute__((address_space(1))) void*)g,
        (__attribute__((address_space(3))) void*)l, 16, 0, 0);
}

// ---------------------------------------------------------------------------
// Input dtype detector (proven R3). flag: 1=bf16, 0=fp32.
// ---------------------------------------------------------------------------
__global__ void detect_dtype(const unsigned short* __restrict__ emb, int* flag) {
    __shared__ int tot;
    if (threadIdx.x == 0) tot = 0;
    __syncthreads();
    int c = 0;
    for (int i = 0; i < 64; i++) {
        unsigned short v = emb[2 * (threadIdx.x * 64 + i)];
        unsigned e = (v >> 7) & 0xFF;
        if (v == 0 || v == 0x8000u || (e >= 97 && e <= 137)) c++;
    }
    atomicAdd(&tot, c);
    __syncthreads();
    if (threadIdx.x == 0) *flag = (tot > 8192) ? 1 : 0;
}

__global__ void convert8(const void* __restrict__ src, short* __restrict__ dst,
                         int n8, const int* __restrict__ flag) {
    int i = blockIdx.x * 256 + threadIdx.x;
    if (i >= n8) return;
    if (*flag) {
        ((bf16x8*)dst)[i] = ((const bf16x8*)src)[i];
    } else {
        const float* f = (const float*)src + (size_t)i * 8;
        bf16x8 o;
#pragma unroll
        for (int j = 0; j < 8; j++) o[j] = f2bf(f[j]);
        ((bf16x8*)dst)[i] = o;
    }
}

// All 4 weights (131072 n8 each) + 4 biases (128 n8 each) in ONE launch.
// Grid = 2050 blocks x 256 = 524800 = 4*131072 + 4*128 exactly.
__global__ void convert_all(
    const void* __restrict__ w0, const void* __restrict__ w1,
    const void* __restrict__ w2, const void* __restrict__ w3,
    const void* __restrict__ b0, const void* __restrict__ b1,
    const void* __restrict__ b2, const void* __restrict__ b3,
    short* dw0, short* dw1, short* dw2, short* dw3,
    short* db0, short* db1, short* db2, short* db3,
    const int* __restrict__ flag)
{
    int i = blockIdx.x * 256 + threadIdx.x;
    const void* src; short* dst; int idx;
    if (i < 524288) {
        int w = i >> 17; idx = i & 131071;
        src = (w == 0) ? w0 : (w == 1) ? w1 : (w == 2) ? w2 : w3;
        dst = (w == 0) ? dw0 : (w == 1) ? dw1 : (w == 2) ? dw2 : dw3;
    } else {
        int j = i - 524288; int b = j >> 7; idx = j & 127;
        src = (b == 0) ? b0 : (b == 1) ? b1 : (b == 2) ? b2 : b3;
        dst = (b == 0) ? db0 : (b == 1) ? db1 : (b == 2) ? db2 : db3;
    }
    if (*flag) {
        ((bf16x8*)dst)[idx] = ((const bf16x8*)src)[idx];
    } else {
        const float* f = (const float*)src + (size_t)idx * 8;
        bf16x8 o;
#pragma unroll
        for (int j = 0; j < 8; j++) o[j] = f2bf(f[j]);
        ((bf16x8*)dst)[idx] = o;
    }
}

// ---------------------------------------------------------------------------
// m97-style GEMM (proven R7): 128x128 tile, BK=32, global_load_lds staging.
// mode: 0 = bf16 natural, 1 = bf16 transposed (Vt), 2 = per *flag dtype.
// ---------------------------------------------------------------------------
__global__ __launch_bounds__(256) void gemm128(
    const short* __restrict__ A,
    const short* __restrict__ B0, const short* __restrict__ B1,
    const short* __restrict__ B2,
    const short* __restrict__ bias0, const short* __restrict__ bias1,
    const short* __restrict__ bias2,
    void* __restrict__ C0, void* __restrict__ C1, void* __restrict__ C2,
    float s0, float s1, float s2,
    int mode0, int mode1, int mode2,
    const int* __restrict__ flag)
{
    constexpr int M = 8192, N = 1024, Kd = 1024, BK = 32;
    __shared__ __align__(16) short As[128 * BK];
    __shared__ __align__(16) short Bs[128 * BK];

    const int z = blockIdx.z;
    const short* B    = (z == 0) ? B0    : (z == 1) ? B1    : B2;
    const short* bias = (z == 0) ? bias0 : (z == 1) ? bias1 : bias2;
    void*  C     = (z == 0) ? C0 : (z == 1) ? C1 : C2;
    float  scale = (z == 0) ? s0 : (z == 1) ? s1 : s2;
    int    mode  = (z == 0) ? mode0 : (z == 1) ? mode1 : mode2;

    const int tid  = threadIdx.x;
    const int lane = tid & 63;
    const int wave = tid >> 6;
    const int lr   = lane & 15;
    const int quad = lane >> 4;
    const int q8   = quad * 8;

    const int m0 = (blockIdx.x >> 3) * 128;
    const int n0 = (blockIdx.x & 7) * 128;
    const int wm = (wave >> 1) * 64;
    const int wn = (wave & 1) * 64;

    const int srow = lane >> 2;
    const int scol = (lane & 3) * 8;

    int fl = 1;
    if (mode == 2) fl = *flag;

    f32x4 acc[4][4];
#pragma unroll
    for (int i = 0; i < 4; i++)
#pragma unroll
        for (int j = 0; j < 4; j++) acc[i][j] = (f32x4){0.f, 0.f, 0.f, 0.f};

    for (int k0 = 0; k0 < Kd; k0 += BK) {
#pragma unroll
        for (int t = 0; t < 2; t++) {
            const int r = wave * 32 + t * 16;
            gload_lds16(A + (size_t)(m0 + r + srow) * Kd + k0 + scol,
                        As + r * BK);
            gload_lds16(B + (size_t)(n0 + r + srow) * Kd + k0 + scol,
                        Bs + r * BK);
        }
        __syncthreads();

        bf16x8 a[4], b[4];
#pragma unroll
        for (int i = 0; i < 4; i++)
            a[i] = *(const bf16x8*)(As + (wm + i * 16 + lr) * BK + q8);
#pragma unroll
        for (int j = 0; j < 4; j++)
            b[j] = *(const bf16x8*)(Bs + (wn + j * 16 + lr) * BK + q8);
#pragma unroll
        for (int i = 0; i < 4; i++)
#pragma unroll
            for (int j = 0; j < 4; j++)
                acc[i][j] = MFMA_BF16(a[i], b[j], acc[i][j]);
        __syncthreads();
    }

#pragma unroll
    for (int j = 0; j < 4; j++) {
        const int col = n0 + wn + j * 16 + lr;
        const float bv = bf2f(bias[col]);
#pragma unroll
        for (int i = 0; i < 4; i++) {
#pragma unroll
            for (int r = 0; r < 4; r++) {
                const int row = m0 + wm + i * 16 + quad * 4 + r;
                const float v = (acc[i][j][r] + bv) * scale;
                if (mode == 1)      ((short*)C)[(size_t)col * M + row] = f2bf(v);
                else if (mode == 0) ((short*)C)[(size_t)row * N + col] = f2bf(v);
                else {
                    if (fl) ((short*)C)[(size_t)row * N + col] = f2bf(v);
                    else    ((float*)C)[(size_t)row * N + col] = v;
                }
            }
        }
    }
}

// ---------------------------------------------------------------------------
// Flash attention R10: 32x32 swapped-operand structure (m214/T12 port).
//  - Each wave owns 32 q-rows; mfma_f32_32x32x16_bf16 throughout.
//  - S^T = mfma(K, Q): lane holds P[q=lane&31][kv subset] LANE-LOCALLY ->
//    softmax numerator + row-sum fully in-register (no cross-lane for P).
//  - P -> PV A-fragments via 16 v_cvt_pk_bf16_f32 + 8 v_permlane32_swap
//    (pure VALU; replaces 16 ds_bpermute + 24 pack ops of R9).
//    Mapping (derived, matches m214): pa[ks] dwords = permswap pairs of
//    cvtpk(st[ks>>1][8(ks&1)+{0,1,2,3}]) x cvtpk(st[ks>>1][8(ks&1)+{4..7}]).
//  - Staging identical to R9: gload_lds DMA, double buffer, counted
//    vmcnt(4), XOR chunk swizzle (LDS row r chunk c holds global c^(r&7)).
//    Fragment reads (b128, 64 lanes) hit the 8-lane/bank floor: conflict-free.
// Aout may alias Q: each wave reads only the 32 Q rows it alone writes.
// ---------------------------------------------------------------------------
__global__ __launch_bounds__(256) void attn_kernel(
    const short* Q, const short* __restrict__ K,
    const short* __restrict__ Vt, short* Aout)
{
    // [buf][0]=K tile [kv 0..63][64 c], [buf][1]=V tile [d 0..63][64 kv]
    __shared__ __align__(16) short lds[2][2][64][64];   // 32 KiB

    const int tid  = threadIdx.x;
    const int lane = tid & 63;
    const int wave = tid >> 6;
    const int l31  = lane & 31;
    const int hi   = lane >> 5;
    const int xr   = l31 & 7;          // row&7 for all fragment rows

    const int qt = blockIdx.x;
    const int bh = blockIdx.y;
    const int b  = bh >> 4, h = bh & 15;
    const int q0 = b * 2048 + qt * 128 + wave * 32;
    const int c0 = h * 64;

    // staging geometry (unchanged from R9)
    const int sr = lane >> 3;
    const int sc = ((lane & 7) ^ sr) * 8;      // shorts
    const int sarr = wave >> 1;                // waves 0,1 -> K; 2,3 -> V

    const short* Kb = K  + (size_t)(b * 2048) * 1024 + c0;
    const short* Vb = Vt + (size_t)c0 * 8192 + b * 2048;

    // Q as B-fragments: lane holds Q[q=l31][c = slot*16 + hi*8 + 0..7]
    bf16x8 qf[4];
#pragma unroll
    for (int slot = 0; slot < 4; slot++)
        qf[slot] = *(const bf16x8*)(Q + (size_t)(q0 + l31) * 1024 + c0 + slot * 16 + hi * 8);

    auto stage = [&](int bufi, int kt) {
#pragma unroll
        for (int t = 0; t < 4; t++) {
            const int r0 = ((wave & 1) * 4 + t) * 8;
            short* dst = &lds[bufi][sarr][r0][0];       // wave-uniform base
            if (sarr == 0)
                gload_lds16(Kb + (size_t)(kt + r0 + sr) * 1024 + sc, dst);
            else
                gload_lds16(Vb + (size_t)(r0 + sr) * 8192 + kt + sc, dst);
        }
    };

    float l_run = 0.f;
    f32x16 o[2];
#pragma unroll
    for (int dblk = 0; dblk < 2; dblk++)
#pragma unroll
        for (int r = 0; r < 16; r++) o[dblk][r] = 0.f;

    stage(0, 0);
    for (int kt = 0; kt < 2048; kt += 64) {
        const int cur = (kt >> 6) & 1;
        stage(cur ^ 1, (kt + 64) & 2047);   // last iter wraps: harmless re-stage
        asm volatile("s_waitcnt vmcnt(4)" ::: "memory");  // tile cur complete
        __builtin_amdgcn_s_barrier();
        __builtin_amdgcn_sched_barrier(0);

        // S^T[kv][q]: st[blk] covers kv = blk*32 + crow(reg,hi), q = l31
        f32x16 st[2];
#pragma unroll
        for (int blk = 0; blk < 2; blk++)
#pragma unroll
            for (int r = 0; r < 16; r++) st[blk][r] = 0.f;

#pragma unroll
        for (int blk = 0; blk < 2; blk++)
#pragma unroll
            for (int slot = 0; slot < 4; slot++) {
                bf16x8 kf = *(const bf16x8*)
                    &lds[cur][0][blk * 32 + l31][(((slot << 1) | hi) ^ xr) * 8];
                st[blk] = MFMA32(kf, qf[slot], st[blk]);
            }

        // exp (log2-domain scores) + lane-local row-sum partial
        float rs = 0.f;
#pragma unroll
        for (int blk = 0; blk < 2; blk++)
#pragma unroll
            for (int r = 0; r < 16; r++) {
                float p = fexp2(st[blk][r]);
                st[blk][r] = p;
                rs += p;
            }
        l_run += rs;

        // P -> A-fragments (cvt_pk + permlane32_swap) fused with PV MFMAs
#pragma unroll
        for (int ks = 0; ks < 4; ks++) {
            const int blk = ks >> 1;
            const int rb  = (ks & 1) * 8;
            int A0 = cvtpk_bf16(st[blk][rb + 0], st[blk][rb + 1]);
            int A1 = cvtpk_bf16(st[blk][rb + 2], st[blk][rb + 3]);
            int B0 = cvtpk_bf16(st[blk][rb + 4], st[blk][rb + 5]);
            int B1 = cvtpk_bf16(st[blk][rb + 6], st[blk][rb + 7]);
            permswap(A0, B0);   // A0 -> dw0 (j0,j1), B0 -> dw2 (j4,j5)
            permswap(A1, B1);   // A1 -> dw1 (j2,j3), B1 -> dw3 (j6,j7)
            i32x4 paw; paw[0] = A0; paw[1] = A1; paw[2] = B0; paw[3] = B1;
            const bf16x8 pf = *(const bf16x8*)&paw;
#pragma unroll
            for (int dblk = 0; dblk < 2; dblk++) {
                bf16x8 vf = *(const bf16x8*)
                    &lds[cur][1][dblk * 32 + l31][(((ks << 1) | hi) ^ xr) * 8];
                o[dblk] = MFMA32(pf, vf, o[dblk]);
            }
        }

        asm volatile("s_waitcnt lgkmcnt(0)" ::: "memory");
        __builtin_amdgcn_sched_barrier(0);
        __builtin_amdgcn_s_barrier();
    }

    // total row-sum: partner half holds complementary kv subset
    float l_tot = l_run + __shfl_xor(l_run, 32);
#pragma unroll
    for (int r = 0; r < 16; r++) {
        const int qrow = (r & 3) + 8 * (r >> 2) + 4 * hi;
        const float inv = 1.f / __shfl(l_tot, qrow);  // lanes 0..31 hold q=lane
#pragma unroll
        for (int dblk = 0; dblk < 2; dblk++)
            Aout[(size_t)(q0 + qrow) * 1024 + c0 + dblk * 32 + l31] =
                f2bf(o[dblk][r] * inv);
    }
}

// ---------------------------------------------------------------------------
extern "C" void kernel_launch(void* const* d_in, const int* in_sizes, int n_in,
                              void* d_out, int out_size, void* d_ws, size_t ws_size,
                              hipStream_t stream)
{
    const size_t MB = (size_t)1024 * 1024;
    char* ws = (char*)d_ws;

    int*   flagp = (int*)ws;                 // [0, 256)
    short* embC  = (short*)(ws + 1 * MB);    // 16 MB [8192][1024]
    short* wC[4] = { (short*)(ws + 17 * MB), (short*)(ws + 19 * MB),
                     (short*)(ws + 21 * MB), (short*)(ws + 23 * MB) };  // 2 MB ea
    short* bC[4] = { (short*)(ws + 25 * MB), (short*)(ws + 25 * MB + 4096),
                     (short*)(ws + 25 * MB + 8192), (short*)(ws + 25 * MB + 12288) };

    short *Qb, *Kb, *Vt, *Ab;
    if (ws_size >= 90 * MB) {
        Qb = (short*)(ws + 26 * MB);
        Kb = (short*)(ws + 42 * MB);
        Vt = (short*)(ws + 58 * MB);
        Ab = (short*)(ws + 74 * MB);
    } else {
        Qb = (short*)(ws + 26 * MB);
        Kb = (short*)d_out;      // dead after attention; final GEMM rewrites
        Vt = (short*)(ws + 42 * MB);
        Ab = Qb;                 // alias: safe per attn_kernel note
    }

    detect_dtype<<<1, 256, 0, stream>>>((const unsigned short*)d_in[0], flagp);

    convert8<<<4096, 256, 0, stream>>>(d_in[0], embC, 1048576, flagp);   // emb
    convert_all<<<2050, 256, 0, stream>>>(
        d_in[1], d_in[3], d_in[5], d_in[7],
        d_in[2], d_in[4], d_in[6], d_in[8],
        wC[0], wC[1], wC[2], wC[3],
        bC[0], bC[1], bC[2], bC[3], flagp);

    dim3 blk(256);
    // Fused QKV; Q scale = log2(e)/8 (log2-domain softmax, see attn header).
    gemm128<<<dim3(512, 1, 3), blk, 0, stream>>>(
        embC, wC[0], wC[1], wC[2], bC[0], bC[1], bC[2],
        Qb, Kb, Vt, 0.18033688011112042f, 1.0f, 1.0f, 0, 0, 1, nullptr);

    attn_kernel<<<dim3(16, 64), blk, 0, stream>>>(Qb, Kb, Vt, Ab);

    gemm128<<<dim3(512, 1, 1), blk, 0, stream>>>(
        Ab, wC[3], nullptr, nullptr, bC[3], nullptr, nullptr,
        d_out, nullptr, nullptr, 1.0f, 0.f, 0.f, 2, 0, 0, flagp);
}

// Round 3
// 324.994 us; speedup vs baseline: 1.1798x; 1.0163x over previous
//
#include <hip/hip_runtime.h>
#include <hip/hip_bf16.h>
#include <math.h>

// bf16 stored as short (raw bits); fp32 accumulate in MFMA.
using bf16x8 = __attribute__((ext_vector_type(8))) short;
using f32x4  = __attribute__((ext_vector_type(4))) float;
using f32x16 = __attribute__((ext_vector_type(16))) float;
using i32x4  = __attribute__((ext_vector_type(4))) int;

#define MFMA_BF16(a, b, c) __builtin_amdgcn_mfma_f32_16x16x32_bf16((a), (b), (c), 0, 0, 0)
#define MFMA32(a, b, c)    __builtin_amdgcn_mfma_f32_32x32x16_bf16((a), (b), (c), 0, 0, 0)

__device__ __forceinline__ float bf2f(short s) {
    union { unsigned u; float f; } v;
    v.u = ((unsigned)(unsigned short)s) << 16;
    return v.f;
}
__device__ __forceinline__ short f2bf(float f) {
    union { float f; unsigned u; } v; v.f = f;
    unsigned r = v.u + 0x7FFF + ((v.u >> 16) & 1);  // round-to-nearest-even
    return (short)(r >> 16);
}
// Native packed f32->bf16 convert (RNE), 1 VALU op for 2 values.
__device__ __forceinline__ int cvtpk_bf16(float lo, float hi) {
    int r;
    asm("v_cvt_pk_bf16_f32 %0, %1, %2" : "=v"(r) : "v"(lo), "v"(hi));
    return r;
}
// v_permlane32_swap_b32: a'[l<32]=a[l], a'[32+i]=b[i]; b'[i]=a[32+i], b'[32+i]=b[32+i].
__device__ __forceinline__ void permswap(int &a, int &b) {
#if __has_builtin(__builtin_amdgcn_permlane32_swap)
    typedef unsigned u32x2v __attribute__((ext_vector_type(2)));
    u32x2v r = __builtin_amdgcn_permlane32_swap((unsigned)a, (unsigned)b, false, false);
    a = (int)r[0]; b = (int)r[1];
#else
    asm volatile("v_permlane32_swap_b32 %0, %1" : "+v"(a), "+v"(b));
#endif
}
// Raw 2^x (v_exp_f32). Q is pre-scaled by log2(e)/8 so this IS exp(score).
__device__ __forceinline__ float fexp2(float x) {
#if __has_builtin(__builtin_amdgcn_exp2f)
    return __builtin_amdgcn_exp2f(x);
#else
    return exp2f(x);
#endif
}

// Async global->LDS DMA, 16B per lane (LDS dest = wave base + lane*16).
__device__ __forceinline__ void gload_lds16(const void* g, void* l) {
    __builtin_amdgcn_global_load_lds(
        (const __attribute__((address_space(1))) void*)g,
        (__attribute__((address_space(3))) void*)l, 16, 0, 0);
}

// ---------------------------------------------------------------------------
// Input dtype detector (proven R3). flag: 1=bf16, 0=fp32.
// ---------------------------------------------------------------------------
__global__ void detect_dtype(const unsigned short* __restrict__ emb, int* flag) {
    __shared__ int tot;
    if (threadIdx.x == 0) tot = 0;
    __syncthreads();
    int c = 0;
    for (int i = 0; i < 64; i++) {
        unsigned short v = emb[2 * (threadIdx.x * 64 + i)];
        unsigned e = (v >> 7) & 0xFF;
        if (v == 0 || v == 0x8000u || (e >= 97 && e <= 137)) c++;
    }
    atomicAdd(&tot, c);
    __syncthreads();
    if (threadIdx.x == 0) *flag = (tot > 8192) ? 1 : 0;
}

__global__ void convert8(const void* __restrict__ src, short* __restrict__ dst,
                         int n8, const int* __restrict__ flag) {
    int i = blockIdx.x * 256 + threadIdx.x;
    if (i >= n8) return;
    if (*flag) {
        ((bf16x8*)dst)[i] = ((const bf16x8*)src)[i];
    } else {
        const float* f = (const float*)src + (size_t)i * 8;
        bf16x8 o;
#pragma unroll
        for (int j = 0; j < 8; j++) o[j] = f2bf(f[j]);
        ((bf16x8*)dst)[i] = o;
    }
}

// All 4 weights (131072 n8 each) + 4 biases (128 n8 each) in ONE launch.
// Grid = 2050 blocks x 256 = 524800 = 4*131072 + 4*128 exactly.
__global__ void convert_all(
    const void* __restrict__ w0, const void* __restrict__ w1,
    const void* __restrict__ w2, const void* __restrict__ w3,
    const void* __restrict__ b0, const void* __restrict__ b1,
    const void* __restrict__ b2, const void* __restrict__ b3,
    short* dw0, short* dw1, short* dw2, short* dw3,
    short* db0, short* db1, short* db2, short* db3,
    const int* __restrict__ flag)
{
    int i = blockIdx.x * 256 + threadIdx.x;
    const void* src; short* dst; int idx;
    if (i < 524288) {
        int w = i >> 17; idx = i & 131071;
        src = (w == 0) ? w0 : (w == 1) ? w1 : (w == 2) ? w2 : w3;
        dst = (w == 0) ? dw0 : (w == 1) ? dw1 : (w == 2) ? dw2 : dw3;
    } else {
        int j = i - 524288; int b = j >> 7; idx = j & 127;
        src = (b == 0) ? b0 : (b == 1) ? b1 : (b == 2) ? b2 : b3;
        dst = (b == 0) ? db0 : (b == 1) ? db1 : (b == 2) ? db2 : db3;
    }
    if (*flag) {
        ((bf16x8*)dst)[idx] = ((const bf16x8*)src)[idx];
    } else {
        const float* f = (const float*)src + (size_t)idx * 8;
        bf16x8 o;
#pragma unroll
        for (int j = 0; j < 8; j++) o[j] = f2bf(f[j]);
        ((bf16x8*)dst)[idx] = o;
    }
}

// ---------------------------------------------------------------------------
// GEMM R11: m97 structure + three latency fixes.
//  - XCD swizzle: swz=(bid&7)*64+(bid>>3); m-panel = swz>>3 -> each XCD owns
//    8 m-panels (2 MB A, L2-resident) x all n, instead of streaming all 16 MB
//    of A through one 4 MB L2 (old mapping: XCD = n-slice).
//  - Double-buffered LDS + counted s_waitcnt vmcnt(4) + raw barriers: next
//    tile's 4 DMA loads stay in flight across the barrier (attn-R9 pattern).
//  - LDS XOR chunk swizzle (both sides, rule 21): LDS row r chunk c holds
//    global chunk c^((r>>1)&3); DMA source pre-swizzled per lane, fragment
//    reads use chunk = quad^((lr>>1)&3). 8-way bank conflict -> 2-way (free).
// mode: 0 = bf16 natural, 1 = bf16 transposed (Vt), 2 = per *flag dtype.
// ---------------------------------------------------------------------------
__global__ __launch_bounds__(256) void gemm128(
    const short* __restrict__ A,
    const short* __restrict__ B0, const short* __restrict__ B1,
    const short* __restrict__ B2,
    const short* __restrict__ bias0, const short* __restrict__ bias1,
    const short* __restrict__ bias2,
    void* __restrict__ C0, void* __restrict__ C1, void* __restrict__ C2,
    float s0, float s1, float s2,
    int mode0, int mode1, int mode2,
    const int* __restrict__ flag)
{
    constexpr int M = 8192, N = 1024, Kd = 1024, BK = 32;
    __shared__ __align__(16) short As[2][128 * BK];
    __shared__ __align__(16) short Bs[2][128 * BK];

    const int z = blockIdx.z;
    const short* B    = (z == 0) ? B0    : (z == 1) ? B1    : B2;
    const short* bias = (z == 0) ? bias0 : (z == 1) ? bias1 : bias2;
    void*  C     = (z == 0) ? C0 : (z == 1) ? C1 : C2;
    float  scale = (z == 0) ? s0 : (z == 1) ? s1 : s2;
    int    mode  = (z == 0) ? mode0 : (z == 1) ? mode1 : mode2;

    const int tid  = threadIdx.x;
    const int lane = tid & 63;
    const int wave = tid >> 6;
    const int lr   = lane & 15;
    const int quad = lane >> 4;

    // XCD-aware bijective swizzle (512 blocks, 8 XCDs; XCD = bid%8).
    const int bid = blockIdx.x;
    const int swz = ((bid & 7) << 6) | (bid >> 3);
    const int m0 = (swz >> 3) * 128;
    const int n0 = (swz & 7) * 128;
    const int wm = (wave >> 1) * 64;
    const int wn = (wave & 1) * 64;

    // staging: lane covers row lane>>2, chunk lane&3; source chunk XOR-swizzled
    const int srow = lane >> 2;
    const int scol = (((lane & 3) ^ ((lane >> 3) & 3)) * 8);
    // fragment read chunk (shorts offset): quad ^ ((lr>>1)&3)
    const int rchunk = (quad ^ ((lr >> 1) & 3)) * 8;

    int fl = 1;
    if (mode == 2) fl = *flag;

    f32x4 acc[4][4];
#pragma unroll
    for (int i = 0; i < 4; i++)
#pragma unroll
        for (int j = 0; j < 4; j++) acc[i][j] = (f32x4){0.f, 0.f, 0.f, 0.f};

    auto stage = [&](int bufi, int k) {
#pragma unroll
        for (int t = 0; t < 2; t++) {
            const int r = wave * 32 + t * 16;
            gload_lds16(A + (size_t)(m0 + r + srow) * Kd + k + scol,
                        &As[bufi][r * BK]);
            gload_lds16(B + (size_t)(n0 + r + srow) * Kd + k + scol,
                        &Bs[bufi][r * BK]);
        }
    };

    stage(0, 0);
    for (int k0 = 0; k0 < Kd; k0 += BK) {
        const int cur = (k0 >> 5) & 1;
        stage(cur ^ 1, (k0 + BK) & (Kd - 1));   // last iter wraps: harmless
        asm volatile("s_waitcnt vmcnt(4)" ::: "memory");  // tile cur complete
        __builtin_amdgcn_s_barrier();
        __builtin_amdgcn_sched_barrier(0);

        bf16x8 a[4], b[4];
#pragma unroll
        for (int i = 0; i < 4; i++)
            a[i] = *(const bf16x8*)(&As[cur][(wm + i * 16 + lr) * BK + rchunk]);
#pragma unroll
        for (int j = 0; j < 4; j++)
            b[j] = *(const bf16x8*)(&Bs[cur][(wn + j * 16 + lr) * BK + rchunk]);
#pragma unroll
        for (int i = 0; i < 4; i++)
#pragma unroll
            for (int j = 0; j < 4; j++)
                acc[i][j] = MFMA_BF16(a[i], b[j], acc[i][j]);

        asm volatile("s_waitcnt lgkmcnt(0)" ::: "memory");
        __builtin_amdgcn_sched_barrier(0);
        __builtin_amdgcn_s_barrier();
    }

#pragma unroll
    for (int j = 0; j < 4; j++) {
        const int col = n0 + wn + j * 16 + lr;
        const float bv = bf2f(bias[col]);
#pragma unroll
        for (int i = 0; i < 4; i++) {
#pragma unroll
            for (int r = 0; r < 4; r++) {
                const int row = m0 + wm + i * 16 + quad * 4 + r;
                const float v = (acc[i][j][r] + bv) * scale;
                if (mode == 1)      ((short*)C)[(size_t)col * M + row] = f2bf(v);
                else if (mode == 0) ((short*)C)[(size_t)row * N + col] = f2bf(v);
                else {
                    if (fl) ((short*)C)[(size_t)row * N + col] = f2bf(v);
                    else    ((float*)C)[(size_t)row * N + col] = v;
                }
            }
        }
    }
}

// ---------------------------------------------------------------------------
// Flash attention R10 (unchanged): 32x32 swapped-operand structure.
//  - Each wave owns 32 q-rows; mfma_f32_32x32x16_bf16 throughout.
//  - S^T = mfma(K, Q): lane holds P[q=lane&31][kv subset] LANE-LOCALLY ->
//    softmax numerator + row-sum fully in-register (no cross-lane for P).
//  - P -> PV A-fragments via 16 v_cvt_pk_bf16_f32 + 8 v_permlane32_swap.
//  - Staging: gload_lds DMA, double buffer, counted vmcnt(4), XOR chunk
//    swizzle (LDS row r chunk c holds global c^(r&7)).
// Aout may alias Q: each wave reads only the 32 Q rows it alone writes.
// ---------------------------------------------------------------------------
__global__ __launch_bounds__(256) void attn_kernel(
    const short* Q, const short* __restrict__ K,
    const short* __restrict__ Vt, short* Aout)
{
    // [buf][0]=K tile [kv 0..63][64 c], [buf][1]=V tile [d 0..63][64 kv]
    __shared__ __align__(16) short lds[2][2][64][64];   // 32 KiB

    const int tid  = threadIdx.x;
    const int lane = tid & 63;
    const int wave = tid >> 6;
    const int l31  = lane & 31;
    const int hi   = lane >> 5;
    const int xr   = l31 & 7;          // row&7 for all fragment rows

    const int qt = blockIdx.x;
    const int bh = blockIdx.y;
    const int b  = bh >> 4, h = bh & 15;
    const int q0 = b * 2048 + qt * 128 + wave * 32;
    const int c0 = h * 64;

    // staging geometry
    const int sr = lane >> 3;
    const int sc = ((lane & 7) ^ sr) * 8;      // shorts
    const int sarr = wave >> 1;                // waves 0,1 -> K; 2,3 -> V

    const short* Kb = K  + (size_t)(b * 2048) * 1024 + c0;
    const short* Vb = Vt + (size_t)c0 * 8192 + b * 2048;

    // Q as B-fragments: lane holds Q[q=l31][c = slot*16 + hi*8 + 0..7]
    bf16x8 qf[4];
#pragma unroll
    for (int slot = 0; slot < 4; slot++)
        qf[slot] = *(const bf16x8*)(Q + (size_t)(q0 + l31) * 1024 + c0 + slot * 16 + hi * 8);

    auto stage = [&](int bufi, int kt) {
#pragma unroll
        for (int t = 0; t < 4; t++) {
            const int r0 = ((wave & 1) * 4 + t) * 8;
            short* dst = &lds[bufi][sarr][r0][0];       // wave-uniform base
            if (sarr == 0)
                gload_lds16(Kb + (size_t)(kt + r0 + sr) * 1024 + sc, dst);
            else
                gload_lds16(Vb + (size_t)(r0 + sr) * 8192 + kt + sc, dst);
        }
    };

    float l_run = 0.f;
    f32x16 o[2];
#pragma unroll
    for (int dblk = 0; dblk < 2; dblk++)
#pragma unroll
        for (int r = 0; r < 16; r++) o[dblk][r] = 0.f;

    stage(0, 0);
    for (int kt = 0; kt < 2048; kt += 64) {
        const int cur = (kt >> 6) & 1;
        stage(cur ^ 1, (kt + 64) & 2047);   // last iter wraps: harmless re-stage
        asm volatile("s_waitcnt vmcnt(4)" ::: "memory");  // tile cur complete
        __builtin_amdgcn_s_barrier();
        __builtin_amdgcn_sched_barrier(0);

        // S^T[kv][q]: st[blk] covers kv = blk*32 + crow(reg,hi), q = l31
        f32x16 st[2];
#pragma unroll
        for (int blk = 0; blk < 2; blk++)
#pragma unroll
            for (int r = 0; r < 16; r++) st[blk][r] = 0.f;

#pragma unroll
        for (int blk = 0; blk < 2; blk++)
#pragma unroll
            for (int slot = 0; slot < 4; slot++) {
                bf16x8 kf = *(const bf16x8*)
                    &lds[cur][0][blk * 32 + l31][(((slot << 1) | hi) ^ xr) * 8];
                st[blk] = MFMA32(kf, qf[slot], st[blk]);
            }

        // exp (log2-domain scores) + lane-local row-sum partial
        float rs = 0.f;
#pragma unroll
        for (int blk = 0; blk < 2; blk++)
#pragma unroll
            for (int r = 0; r < 16; r++) {
                float p = fexp2(st[blk][r]);
                st[blk][r] = p;
                rs += p;
            }
        l_run += rs;

        // P -> A-fragments (cvt_pk + permlane32_swap) fused with PV MFMAs
#pragma unroll
        for (int ks = 0; ks < 4; ks++) {
            const int blk = ks >> 1;
            const int rb  = (ks & 1) * 8;
            int A0 = cvtpk_bf16(st[blk][rb + 0], st[blk][rb + 1]);
            int A1 = cvtpk_bf16(st[blk][rb + 2], st[blk][rb + 3]);
            int B0 = cvtpk_bf16(st[blk][rb + 4], st[blk][rb + 5]);
            int B1 = cvtpk_bf16(st[blk][rb + 6], st[blk][rb + 7]);
            permswap(A0, B0);   // A0 -> dw0 (j0,j1), B0 -> dw2 (j4,j5)
            permswap(A1, B1);   // A1 -> dw1 (j2,j3), B1 -> dw3 (j6,j7)
            i32x4 paw; paw[0] = A0; paw[1] = A1; paw[2] = B0; paw[3] = B1;
            const bf16x8 pf = *(const bf16x8*)&paw;
#pragma unroll
            for (int dblk = 0; dblk < 2; dblk++) {
                bf16x8 vf = *(const bf16x8*)
                    &lds[cur][1][dblk * 32 + l31][(((ks << 1) | hi) ^ xr) * 8];
                o[dblk] = MFMA32(pf, vf, o[dblk]);
            }
        }

        asm volatile("s_waitcnt lgkmcnt(0)" ::: "memory");
        __builtin_amdgcn_sched_barrier(0);
        __builtin_amdgcn_s_barrier();
    }

    // total row-sum: partner half holds complementary kv subset
    float l_tot = l_run + __shfl_xor(l_run, 32);
#pragma unroll
    for (int r = 0; r < 16; r++) {
        const int qrow = (r & 3) + 8 * (r >> 2) + 4 * hi;
        const float inv = 1.f / __shfl(l_tot, qrow);  // lanes 0..31 hold q=lane
#pragma unroll
        for (int dblk = 0; dblk < 2; dblk++)
            Aout[(size_t)(q0 + qrow) * 1024 + c0 + dblk * 32 + l31] =
                f2bf(o[dblk][r] * inv);
    }
}

// ---------------------------------------------------------------------------
extern "C" void kernel_launch(void* const* d_in, const int* in_sizes, int n_in,
                              void* d_out, int out_size, void* d_ws, size_t ws_size,
                              hipStream_t stream)
{
    const size_t MB = (size_t)1024 * 1024;
    char* ws = (char*)d_ws;

    int*   flagp = (int*)ws;                 // [0, 256)
    short* embC  = (short*)(ws + 1 * MB);    // 16 MB [8192][1024]
    short* wC[4] = { (short*)(ws + 17 * MB), (short*)(ws + 19 * MB),
                     (short*)(ws + 21 * MB), (short*)(ws + 23 * MB) };  // 2 MB ea
    short* bC[4] = { (short*)(ws + 25 * MB), (short*)(ws + 25 * MB + 4096),
                     (short*)(ws + 25 * MB + 8192), (short*)(ws + 25 * MB + 12288) };

    short *Qb, *Kb, *Vt, *Ab;
    if (ws_size >= 90 * MB) {
        Qb = (short*)(ws + 26 * MB);
        Kb = (short*)(ws + 42 * MB);
        Vt = (short*)(ws + 58 * MB);
        Ab = (short*)(ws + 74 * MB);
    } else {
        Qb = (short*)(ws + 26 * MB);
        Kb = (short*)d_out;      // dead after attention; final GEMM rewrites
        Vt = (short*)(ws + 42 * MB);
        Ab = Qb;                 // alias: safe per attn_kernel note
    }

    detect_dtype<<<1, 256, 0, stream>>>((const unsigned short*)d_in[0], flagp);

    convert8<<<4096, 256, 0, stream>>>(d_in[0], embC, 1048576, flagp);   // emb
    convert_all<<<2050, 256, 0, stream>>>(
        d_in[1], d_in[3], d_in[5], d_in[7],
        d_in[2], d_in[4], d_in[6], d_in[8],
        wC[0], wC[1], wC[2], wC[3],
        bC[0], bC[1], bC[2], bC[3], flagp);

    dim3 blk(256);
    // Fused QKV; Q scale = log2(e)/8 (log2-domain softmax, see attn header).
    gemm128<<<dim3(512, 1, 3), blk, 0, stream>>>(
        embC, wC[0], wC[1], wC[2], bC[0], bC[1], bC[2],
        Qb, Kb, Vt, 0.18033688011112042f, 1.0f, 1.0f, 0, 0, 1, nullptr);

    attn_kernel<<<dim3(16, 64), blk, 0, stream>>>(Qb, Kb, Vt, Ab);

    gemm128<<<dim3(512, 1, 1), blk, 0, stream>>>(
        Ab, wC[3], nullptr, nullptr, bC[3], nullptr, nullptr,
        d_out, nullptr, nullptr, 1.0f, 0.f, 0.f, 2, 0, 0, flagp);
}